// Round 6
// baseline (309.410 us; speedup 1.0000x reference)
//
#include <hip/hip_runtime.h>

typedef __attribute__((ext_vector_type(8)))  short short8;   // 8 bf16 (4 VGPRs)
typedef __attribute__((ext_vector_type(16))) float f32x16;   // 32x32 MFMA acc
typedef unsigned short ushort_t;
typedef unsigned int uint32;
typedef unsigned long long uint64_hip;

#define NROWS 8192
#define NCODE 8192
#define DIM   512

// ---------------- d_out layout (floats) ----------------
#define OUT_Q      0
#define OUT_LOSS   4194304
#define OUT_IDX    4194305
#define OUT_MIND   4202497
#define OUT_COMMIT 4210689

// ---------------- ws layout (floats) ----------------
#define WS_ENORM  0           // 8192 floats
#define WS_KEYS   8192        // 8192 uint64 = 16384 floats
#define WS_LPART  24576       // 2048 floats
#define WS_BHI    26624       // 8192*512 bf16 = 2097152 floats
#define WS_BLO    2123776     // same
// total 4220928 floats = 16.9 MB

// ===========================================================================
__device__ inline uint32 bf16_rne(float f) {
    uint32 u = __float_as_uint(f);
    return (u + 0x7FFFu + ((u >> 16) & 1u)) >> 16;
}

__device__ inline void gload16(const ushort_t* g, ushort_t* l) {
    __builtin_amdgcn_global_load_lds(
        (const __attribute__((address_space(1))) void*)g,
        (__attribute__((address_space(3))) void*)l, 16, 0, 0);
}

// ===========================================================================
// Kernel 1: convert x and codebook into fragment-ordered bf16 hi/lo tiles.
// Tile = 128 rows x 16 k = 4 KB (2048 ushorts), 4 chunks of 512:
//   tile = (row>>7)*32 + (k>>4); chunk c = (row&127)>>5;
//   lane L = (row&31) + 32*((k>>3)&1), holding 8 consecutive k.
// This IS the mfma_32x32x16 A/B fragment order (verified rounds 3/4/5).
// Also initializes the per-row argmin keys to +inf.
__global__ __launch_bounds__(256) void conv_kernel(const float* __restrict__ x,
                                                   const float* __restrict__ cb,
                                                   ushort_t* __restrict__ ahi,
                                                   ushort_t* __restrict__ alo,
                                                   ushort_t* __restrict__ bhi,
                                                   ushort_t* __restrict__ blo,
                                                   float* __restrict__ enorm,
                                                   uint64_hip* __restrict__ keys) {
    int gid  = blockIdx.x * 256 + threadIdx.x;   // 0..1048575
    if (gid < NROWS) keys[gid] = ~0ull;          // argmin key init
    bool isA = gid < 524288;
    int g    = isA ? gid : gid - 524288;
    int row  = g >> 6;
    int lane = g & 63;
    int k0   = lane * 8;
    const float* src = (isA ? x : cb) + (size_t)row * DIM + k0;
    float v[8];
    *(float4*)&v[0] = *(const float4*)src;
    *(float4*)&v[4] = *(const float4*)(src + 4);
    float s = 0.0f;
    uint32 h[8], l[8];
    #pragma unroll
    for (int i = 0; i < 8; ++i) {
        s += v[i] * v[i];
        h[i] = bf16_rne(v[i]);
        float hf = __uint_as_float(h[i] << 16);
        l[i] = bf16_rne(v[i] - hf);
    }
    int tile = (row >> 7) * 32 + (k0 >> 4);
    int c    = (row & 127) >> 5;
    int L    = (row & 31) + (((k0 >> 3) & 1) << 5);
    size_t off = (size_t)tile * 2048 + c * 512 + L * 8;   // ushort units
    uint4 ph, pl;
    ph.x = h[0] | (h[1] << 16); ph.y = h[2] | (h[3] << 16);
    ph.z = h[4] | (h[5] << 16); ph.w = h[6] | (h[7] << 16);
    pl.x = l[0] | (l[1] << 16); pl.y = l[2] | (l[3] << 16);
    pl.z = l[4] | (l[5] << 16); pl.w = l[6] | (l[7] << 16);
    if (isA) {
        *(uint4*)(ahi + off) = ph;
        *(uint4*)(alo + off) = pl;
    } else {
        *(uint4*)(bhi + off) = ph;
        *(uint4*)(blo + off) = pl;
        #pragma unroll
        for (int o = 32; o > 0; o >>= 1) s += __shfl_down(s, o);
        if (lane == 0) enorm[row] = s;
    }
}

// ===========================================================================
// Kernel 2: MFMA distance-GEMM + per-row argmin, one 128x256 output tile per
// block with FULL K=512 (no persistent best registers; single epilogue).
// grid 2048, block 256 = 4 waves in 2x2; wave tile 64 rows x 128 cols
// (2x4 of 32x32x16) -> 12 ds_read_b128 per 24 MFMA (ratio 2.0; LDS pipe at
// ~74% of MFMA pipe, MFMA-bound).
// LDS: 2 x 24 KB double-buffered staging (BK=16) + 2 KB cand = 50 KB ->
// 2 blocks/CU; VGPR: 128 acc (AGPR) + ~48 frag -> 2 waves/SIMD.
// XCD swizzle: XCD j=q%8 gets 8 resident bx (2 MB A) x 4 by (2 MB B) = L2.
__global__ __launch_bounds__(256, 2) void vq_mfma_kernel(
        const ushort_t* __restrict__ ahi, const ushort_t* __restrict__ alo,
        const ushort_t* __restrict__ bhi, const ushort_t* __restrict__ blo,
        const float* __restrict__ enorm,
        uint64_hip* __restrict__ keys) {
    __shared__ __align__(16) ushort_t smem[2][12288];   // 2 x 24 KB staging
    __shared__ uint64_hip cand[256];                    // 2 KB: [wc][row]

    const int tid  = threadIdx.x;
    const int wave = tid >> 6, lane = tid & 63;
    const int l31  = lane & 31, half = lane >> 5;
    const int wr = wave >> 1, wc = wave & 1;
    const int q  = blockIdx.x;
    const int bx = q >> 5;                       // 0..63 row block
    const int by = (q & 7) * 4 + ((q >> 3) & 3); // 0..31 col block (256 cols)
    const int so = tid * 8;                      // staging ushort offset (16 B/thr)

    cand[tid] = ~0ull;

    // staging-source base pointers (n-dependent part added per iter)
    const ushort_t* pa_hi = ahi + (size_t)bx * 65536 + so;   // bx*32*2048
    const ushort_t* pa_lo = alo + (size_t)bx * 65536 + so;
    const ushort_t* pb_hi = bhi + (size_t)by * 131072 + so;  // (by*2)*32*2048
    const ushort_t* pb_lo = blo + (size_t)by * 131072 + so;

    // fragment read offsets within a 24 KB buffer (ushort units):
    // [0,2048) Ahi | [2048,4096) Alo | [4096,8192) Bhi | [8192,12288) Blo
    const int ao = wr * 1024 + lane * 8;          // (wr*2)*512
    const int bo = 4096 + wc * 2048 + lane * 8;

    f32x16 acc[2][4];
    #pragma unroll
    for (int i = 0; i < 2; ++i)
        #pragma unroll
        for (int j = 0; j < 4; ++j)
            #pragma unroll
            for (int r = 0; r < 16; ++r) acc[i][j][r] = 0.0f;

    auto stage = [&](int n) {
        const int off = n * 2048;
        ushort_t* S = &smem[n & 1][0];
        gload16(pa_hi + off,         S + so);
        gload16(pa_lo + off,         S + 2048 + so);
        gload16(pb_hi + off,         S + 4096 + so);
        gload16(pb_hi + 65536 + off, S + 6144 + so);
        gload16(pb_lo + off,         S + 8192 + so);
        gload16(pb_lo + 65536 + off, S + 10240 + so);
    };

    stage(0);
    for (int n = 0; n < 32; ++n) {
        __syncthreads();                 // stage(n) drained; buf (n+1)&1 free
        if (n + 1 < 32) stage(n + 1);    // async into other buffer

        const ushort_t* S = &smem[n & 1][0];
        short8 ah[2], al[2], bh[4], bl[4];
        #pragma unroll
        for (int ti = 0; ti < 2; ++ti) {
            ah[ti] = *(const short8*)&S[ao + ti * 512];
            al[ti] = *(const short8*)&S[2048 + ao + ti * 512];
        }
        #pragma unroll
        for (int tj = 0; tj < 4; ++tj) {
            bh[tj] = *(const short8*)&S[bo + tj * 512];
            bl[tj] = *(const short8*)&S[4096 + bo + tj * 512];
        }
        #pragma unroll
        for (int ti = 0; ti < 2; ++ti)
            #pragma unroll
            for (int tj = 0; tj < 4; ++tj) {
                acc[ti][tj] = __builtin_amdgcn_mfma_f32_32x32x16_bf16(
                    ah[ti], bh[tj], acc[ti][tj], 0, 0, 0);
                acc[ti][tj] = __builtin_amdgcn_mfma_f32_32x32x16_bf16(
                    ah[ti], bl[tj], acc[ti][tj], 0, 0, 0);
                acc[ti][tj] = __builtin_amdgcn_mfma_f32_32x32x16_bf16(
                    al[ti], bh[tj], acc[ti][tj], 0, 0, 0);
            }
    }

    // ---- single epilogue: dist' = ||e||^2 - 2*dot (xn drops out of argmin) ----
    float en[4];
    int   col[4];
    #pragma unroll
    for (int tj = 0; tj < 4; ++tj) {
        col[tj] = by * 256 + wc * 128 + tj * 32 + l31;
        en[tj]  = enorm[col[tj]];
    }
    #pragma unroll
    for (int ti = 0; ti < 2; ++ti) {
        #pragma unroll
        for (int reg = 0; reg < 16; ++reg) {
            uint64_hip kbest = ~0ull;
            #pragma unroll
            for (int tj = 0; tj < 4; ++tj) {
                float d = en[tj] - 2.0f * acc[ti][tj][reg];
                uint32 u = __float_as_uint(d);
                u = ((int)u < 0) ? ~u : (u | 0x80000000u);
                uint64_hip k = ((uint64_hip)u << 13) | (uint32)col[tj];
                if (k < kbest) kbest = k;
            }
            #pragma unroll
            for (int m = 1; m <= 16; m <<= 1) {
                uint64_hip k2 = __shfl_xor(kbest, m);
                if (k2 < kbest) kbest = k2;
            }
            if (l31 == 0) {
                int row = wr * 64 + ti * 32 + (reg & 3) + 8 * (reg >> 2) + 4 * half;
                cand[wc * 128 + row] = kbest;
            }
        }
    }
    __syncthreads();
    if (tid < 128) {
        uint64_hip a = cand[tid];
        uint64_hip b = cand[128 + tid];
        atomicMin(&keys[(size_t)bx * 128 + tid], a < b ? a : b);
    }
}

// ===========================================================================
// Kernel 3: decode key -> idx, gather codebook row, exact fp32 ||x-e||^2 ->
// min_distances + loss partials. One 64-lane group per row.
__global__ __launch_bounds__(256) void finish_kernel(const float* __restrict__ x,
                                                     const float* __restrict__ cb,
                                                     const uint64_hip* __restrict__ keys,
                                                     float* __restrict__ out_idx,
                                                     float* __restrict__ qout,
                                                     float* __restrict__ out_mind,
                                                     float* __restrict__ lpart) {
    __shared__ float sred[4];
    int row  = blockIdx.x * 4 + (threadIdx.x >> 6);
    int lane = threadIdx.x & 63;
    int idx  = (int)(keys[row] & 0x1FFFull);
    if (lane == 0) out_idx[row] = (float)idx;

    const float4* e4 = (const float4*)(cb + (size_t)idx * DIM);
    const float4* x4 = (const float4*)(x + (size_t)row * DIM);
    float4* q4 = (float4*)(qout + (size_t)row * DIM);
    float s = 0.0f;
    #pragma unroll
    for (int u = 0; u < 2; ++u) {
        float4 e  = e4[lane + u * 64];
        float4 xv = x4[lane + u * 64];
        q4[lane + u * 64] = e;
        float dx = xv.x - e.x, dy = xv.y - e.y, dz = xv.z - e.z, dw = xv.w - e.w;
        s += dx * dx + dy * dy + dz * dz + dw * dw;
    }
    #pragma unroll
    for (int o = 32; o > 0; o >>= 1) s += __shfl_down(s, o);
    if (lane == 0) { sred[threadIdx.x >> 6] = s; out_mind[row] = s; }
    __syncthreads();
    if (threadIdx.x == 0) lpart[blockIdx.x] = sred[0] + sred[1] + sred[2] + sred[3];
}

// ===========================================================================
// Kernel 4: final loss. loss_vq == loss_commit numerically => loss = 1.25*commit
__global__ __launch_bounds__(256) void loss_kernel(const float* __restrict__ lpart,
                                                   float* __restrict__ out_loss,
                                                   float* __restrict__ out_commit) {
    __shared__ float sm[256];
    float s = 0.0f;
    for (int i = threadIdx.x; i < 2048; i += 256) s += lpart[i];
    sm[threadIdx.x] = s;
    __syncthreads();
    #pragma unroll
    for (int o = 128; o > 0; o >>= 1) {
        if (threadIdx.x < o) sm[threadIdx.x] += sm[threadIdx.x + o];
        __syncthreads();
    }
    if (threadIdx.x == 0) {
        *out_commit = sm[0];
        *out_loss   = 1.25f * sm[0];
    }
}

// ===========================================================================
extern "C" void kernel_launch(void* const* d_in, const int* in_sizes, int n_in,
                              void* d_out, int out_size, void* d_ws, size_t ws_size,
                              hipStream_t stream) {
    const float* x  = (const float*)d_in[0];
    const float* cb = (const float*)d_in[1];
    float* out = (float*)d_out;
    float* ws  = (float*)d_ws;

    // A hi/lo staged in the quantized-output region (rewritten by finish_kernel)
    ushort_t* ahi = (ushort_t*)d_out;
    ushort_t* alo = (ushort_t*)d_out + 4194304;
    ushort_t* bhi = (ushort_t*)(ws + WS_BHI);
    ushort_t* blo = (ushort_t*)(ws + WS_BLO);
    float*      enorm = ws + WS_ENORM;
    uint64_hip* keys  = (uint64_hip*)(ws + WS_KEYS);
    float*      lpart = ws + WS_LPART;

    conv_kernel<<<4096, 256, 0, stream>>>(x, cb, ahi, alo, bhi, blo, enorm, keys);
    vq_mfma_kernel<<<2048, 256, 0, stream>>>(ahi, alo, bhi, blo, enorm, keys);
    finish_kernel<<<NROWS / 4, 256, 0, stream>>>(x, cb, keys,
                                                 out + OUT_IDX, out + OUT_Q,
                                                 out + OUT_MIND, lpart);
    loss_kernel<<<1, 256, 0, stream>>>(lpart, out + OUT_LOSS, out + OUT_COMMIT);
}

// Round 7
// 303.320 us; speedup vs baseline: 1.0201x; 1.0201x over previous
//
#include <hip/hip_runtime.h>

typedef __attribute__((ext_vector_type(8)))  short short8;   // 8 bf16 (4 VGPRs)
typedef __attribute__((ext_vector_type(16))) float f32x16;   // 32x32 MFMA acc
typedef unsigned short ushort_t;
typedef unsigned int uint32;
typedef unsigned long long uint64_hip;

#define NROWS 8192
#define NCODE 8192
#define DIM   512

// ---------------- d_out layout (floats) ----------------
#define OUT_Q      0
#define OUT_LOSS   4194304
#define OUT_IDX    4194305
#define OUT_MIND   4202497
#define OUT_COMMIT 4210689

// ---------------- ws layout (floats) ----------------
#define WS_ENORM  0           // 8192 floats
#define WS_KEYS   8192        // 8192 uint64 = 16384 floats
#define WS_LPART  24576       // 2048 floats
#define WS_BHI    26624       // 8192*512 bf16 = 2097152 floats
#define WS_BLO    2123776     // same
// total 16.9 MB

// ===========================================================================
__device__ inline uint32 bf16_rne(float f) {
    uint32 u = __float_as_uint(f);
    return (u + 0x7FFFu + ((u >> 16) & 1u)) >> 16;
}

__device__ inline void gload16(const ushort_t* g, ushort_t* l) {
    __builtin_amdgcn_global_load_lds(
        (const __attribute__((address_space(1))) void*)g,
        (__attribute__((address_space(3))) void*)l, 16, 0, 0);
}

// ===========================================================================
// Kernel 1: convert x and codebook into fragment-ordered bf16 hi/lo tiles.
// Tile = 128 rows x 16 k = 4 KB (2048 ushorts), 4 chunks of 512:
//   tile = (row>>7)*32 + (k>>4); chunk c = (row&127)>>5;
//   lane L = (row&31) + 32*((k>>3)&1), holding 8 consecutive k.
// (mfma_32x32x16 A/B fragment order — verified rounds 3-6.)
__global__ __launch_bounds__(256) void conv_kernel(const float* __restrict__ x,
                                                   const float* __restrict__ cb,
                                                   ushort_t* __restrict__ ahi,
                                                   ushort_t* __restrict__ alo,
                                                   ushort_t* __restrict__ bhi,
                                                   ushort_t* __restrict__ blo,
                                                   float* __restrict__ enorm,
                                                   uint64_hip* __restrict__ keys) {
    int gid  = blockIdx.x * 256 + threadIdx.x;   // 0..1048575
    if (gid < NROWS) keys[gid] = ~0ull;          // argmin key init
    bool isA = gid < 524288;
    int g    = isA ? gid : gid - 524288;
    int row  = g >> 6;
    int lane = g & 63;
    int k0   = lane * 8;
    const float* src = (isA ? x : cb) + (size_t)row * DIM + k0;
    float v[8];
    *(float4*)&v[0] = *(const float4*)src;
    *(float4*)&v[4] = *(const float4*)(src + 4);
    float s = 0.0f;
    uint32 h[8], l[8];
    #pragma unroll
    for (int i = 0; i < 8; ++i) {
        s += v[i] * v[i];
        h[i] = bf16_rne(v[i]);
        float hf = __uint_as_float(h[i] << 16);
        l[i] = bf16_rne(v[i] - hf);
    }
    int tile = (row >> 7) * 32 + (k0 >> 4);
    int c    = (row & 127) >> 5;
    int L    = (row & 31) + (((k0 >> 3) & 1) << 5);
    size_t off = (size_t)tile * 2048 + c * 512 + L * 8;   // ushort units
    uint4 ph, pl;
    ph.x = h[0] | (h[1] << 16); ph.y = h[2] | (h[3] << 16);
    ph.z = h[4] | (h[5] << 16); ph.w = h[6] | (h[7] << 16);
    pl.x = l[0] | (l[1] << 16); pl.y = l[2] | (l[3] << 16);
    pl.z = l[4] | (l[5] << 16); pl.w = l[6] | (l[7] << 16);
    if (isA) {
        *(uint4*)(ahi + off) = ph;
        *(uint4*)(alo + off) = pl;
    } else {
        *(uint4*)(bhi + off) = ph;
        *(uint4*)(blo + off) = pl;
        #pragma unroll
        for (int o = 32; o > 0; o >>= 1) s += __shfl_down(s, o);
        if (lane == 0) enorm[row] = s;
    }
}

// ===========================================================================
// Kernel 2: MFMA distance-GEMM + fused per-row argmin.
// grid 512 (ONE generation, 2 blocks/CU), block 256 = 4 waves in 2x2;
// wave tile 64 rows x 128 cols (2x4 of 32x32x16): 12 ds_read_b128 per
// 24 MFMA per barrier interval (ratio 2.0, conflict-free — round-6 inner loop).
// Block covers 128 rows x 1024 cols as 4 sequential 256-col strips, full
// K=512 each (32 BK=16 steps); per-strip epilogue: pack sortable key,
// 5-step shfl_xor butterfly, race-free LDS cand RMW (no persistent best regs).
// LDS: 2 x 24 KB dbuf staging + 2 KB cand = 50 KB. VGPR ~100 + AGPR 128.
// XCD swizzle (round-3): XCD j = q%8 hosts bx in [8j,8j+8) -> 2 MB A resident.
__global__ __launch_bounds__(256, 2) void vq_mfma_kernel(
        const ushort_t* __restrict__ ahi, const ushort_t* __restrict__ alo,
        const ushort_t* __restrict__ bhi, const ushort_t* __restrict__ blo,
        const float* __restrict__ enorm,
        uint64_hip* __restrict__ keys) {
    __shared__ __align__(16) ushort_t smem[2][12288];   // 2 x 24 KB staging
    __shared__ uint64_hip cand[256];                    // 2 KB: [wc][row]

    const int tid  = threadIdx.x;
    const int wave = tid >> 6, lane = tid & 63;
    const int l31  = lane & 31, half = lane >> 5;
    const int wr = wave >> 1, wc = wave & 1;
    const int q  = blockIdx.x;
    const int bx = (q & 7) * 8 + (q >> 6);    // 0..63 row block; XCD = q%8
    const int bq = (q >> 3) & 7;              // 0..7 col quarter (1024 cols)
    const int so = tid * 8;                   // staging ushort offset (16 B/thr)

    cand[tid] = ~0ull;

    // fragment read offsets within a 24 KB buffer (ushort units):
    // [0,2048) Ahi | [2048,4096) Alo | [4096,8192) Bhi(t0,t1) | [8192,12288) Blo
    const int ao = wr * 1024 + lane * 8;
    const int bo = 4096 + wc * 2048 + lane * 8;

    f32x16 acc[2][4];
    #pragma unroll
    for (int i = 0; i < 2; ++i)
        #pragma unroll
        for (int j = 0; j < 4; ++j)
            #pragma unroll
            for (int r = 0; r < 16; ++r) acc[i][j][r] = 0.0f;

    auto stage = [&](int n) {
        const int kb = n & 31;
        const size_t at = ((size_t)(bx * 32 + kb)) * 2048;
        const size_t bt = ((size_t)((bq * 8 + (n >> 5) * 2) * 32 + kb)) * 2048;
        ushort_t* S = &smem[n & 1][0];
        gload16(ahi + at + so,         S + so);
        gload16(alo + at + so,         S + 2048 + so);
        gload16(bhi + bt + so,         S + 4096 + so);
        gload16(bhi + bt + 65536 + so, S + 6144 + so);
        gload16(blo + bt + so,         S + 8192 + so);
        gload16(blo + bt + 65536 + so, S + 10240 + so);
    };

    stage(0);
    for (int n = 0; n < 128; ++n) {
        __syncthreads();                  // stage(n) drained; buf (n+1)&1 free
        if (n + 1 < 128) stage(n + 1);    // async into other buffer

        const ushort_t* S = &smem[n & 1][0];
        short8 ah[2], al[2], bh[4], bl[4];
        #pragma unroll
        for (int ti = 0; ti < 2; ++ti) {
            ah[ti] = *(const short8*)&S[ao + ti * 512];
            al[ti] = *(const short8*)&S[2048 + ao + ti * 512];
        }
        #pragma unroll
        for (int tj = 0; tj < 4; ++tj) {
            bh[tj] = *(const short8*)&S[bo + tj * 512];
            bl[tj] = *(const short8*)&S[4096 + bo + tj * 512];
        }
        #pragma unroll
        for (int ti = 0; ti < 2; ++ti)
            #pragma unroll
            for (int tj = 0; tj < 4; ++tj) {
                acc[ti][tj] = __builtin_amdgcn_mfma_f32_32x32x16_bf16(
                    ah[ti], bh[tj], acc[ti][tj], 0, 0, 0);
                acc[ti][tj] = __builtin_amdgcn_mfma_f32_32x32x16_bf16(
                    ah[ti], bl[tj], acc[ti][tj], 0, 0, 0);
                acc[ti][tj] = __builtin_amdgcn_mfma_f32_32x32x16_bf16(
                    al[ti], bh[tj], acc[ti][tj], 0, 0, 0);
            }

        if ((n & 31) == 31) {
            // ---- strip epilogue: dist' = ||e||^2 - 2*dot (xn drops out) ----
            const int ct = n >> 5;
            const int colbase = bq * 1024 + ct * 256 + wc * 128;
            float en[4];
            int   col[4];
            #pragma unroll
            for (int tj = 0; tj < 4; ++tj) {
                col[tj] = colbase + tj * 32 + l31;
                en[tj]  = enorm[col[tj]];
            }
            #pragma unroll
            for (int ti = 0; ti < 2; ++ti) {
                #pragma unroll
                for (int reg = 0; reg < 16; ++reg) {
                    uint64_hip kbest = ~0ull;
                    #pragma unroll
                    for (int tj = 0; tj < 4; ++tj) {
                        float d = en[tj] - 2.0f * acc[ti][tj][reg];
                        uint32 u = __float_as_uint(d);
                        u = ((int)u < 0) ? ~u : (u | 0x80000000u);
                        uint64_hip k = ((uint64_hip)u << 13) | (uint32)col[tj];
                        if (k < kbest) kbest = k;
                    }
                    #pragma unroll
                    for (int m = 1; m <= 16; m <<= 1) {
                        uint64_hip k2 = __shfl_xor(kbest, m);
                        if (k2 < kbest) kbest = k2;
                    }
                    if (l31 == 0) {
                        int row = wr * 64 + ti * 32 + (reg & 3) + 8 * (reg >> 2) + 4 * half;
                        uint64_hip old = cand[wc * 128 + row];   // wave-private slot: no race
                        if (kbest < old) cand[wc * 128 + row] = kbest;
                    }
                }
            }
            #pragma unroll
            for (int i = 0; i < 2; ++i)
                #pragma unroll
                for (int j = 0; j < 4; ++j)
                    #pragma unroll
                    for (int r = 0; r < 16; ++r) acc[i][j][r] = 0.0f;
        }
    }

    __syncthreads();
    if (tid < 128) {
        uint64_hip a = cand[tid];
        uint64_hip b = cand[128 + tid];
        atomicMin(&keys[(size_t)bx * 128 + tid], a < b ? a : b);
    }
}

// ===========================================================================
// Kernel 3: decode key -> idx, gather codebook row, exact fp32 ||x-e||^2 ->
// min_distances + loss partials. One 64-lane group per row.
__global__ __launch_bounds__(256) void finish_kernel(const float* __restrict__ x,
                                                     const float* __restrict__ cb,
                                                     const uint64_hip* __restrict__ keys,
                                                     float* __restrict__ out_idx,
                                                     float* __restrict__ qout,
                                                     float* __restrict__ out_mind,
                                                     float* __restrict__ lpart) {
    __shared__ float sred[4];
    int row  = blockIdx.x * 4 + (threadIdx.x >> 6);
    int lane = threadIdx.x & 63;
    int idx  = (int)(keys[row] & 0x1FFFull);
    if (lane == 0) out_idx[row] = (float)idx;

    const float4* e4 = (const float4*)(cb + (size_t)idx * DIM);
    const float4* x4 = (const float4*)(x + (size_t)row * DIM);
    float4* q4 = (float4*)(qout + (size_t)row * DIM);
    float s = 0.0f;
    #pragma unroll
    for (int u = 0; u < 2; ++u) {
        float4 e  = e4[lane + u * 64];
        float4 xv = x4[lane + u * 64];
        q4[lane + u * 64] = e;
        float dx = xv.x - e.x, dy = xv.y - e.y, dz = xv.z - e.z, dw = xv.w - e.w;
        s += dx * dx + dy * dy + dz * dz + dw * dw;
    }
    #pragma unroll
    for (int o = 32; o > 0; o >>= 1) s += __shfl_down(s, o);
    if (lane == 0) { sred[threadIdx.x >> 6] = s; out_mind[row] = s; }
    __syncthreads();
    if (threadIdx.x == 0) lpart[blockIdx.x] = sred[0] + sred[1] + sred[2] + sred[3];
}

// ===========================================================================
// Kernel 4: final loss. loss_vq == loss_commit numerically => loss = 1.25*commit
__global__ __launch_bounds__(256) void loss_kernel(const float* __restrict__ lpart,
                                                   float* __restrict__ out_loss,
                                                   float* __restrict__ out_commit) {
    __shared__ float sm[256];
    float s = 0.0f;
    for (int i = threadIdx.x; i < 2048; i += 256) s += lpart[i];
    sm[threadIdx.x] = s;
    __syncthreads();
    #pragma unroll
    for (int o = 128; o > 0; o >>= 1) {
        if (threadIdx.x < o) sm[threadIdx.x] += sm[threadIdx.x + o];
        __syncthreads();
    }
    if (threadIdx.x == 0) {
        *out_commit = sm[0];
        *out_loss   = 1.25f * sm[0];
    }
}

// ===========================================================================
extern "C" void kernel_launch(void* const* d_in, const int* in_sizes, int n_in,
                              void* d_out, int out_size, void* d_ws, size_t ws_size,
                              hipStream_t stream) {
    const float* x  = (const float*)d_in[0];
    const float* cb = (const float*)d_in[1];
    float* out = (float*)d_out;
    float* ws  = (float*)d_ws;

    // A hi/lo staged in the quantized-output region (rewritten by finish_kernel)
    ushort_t* ahi = (ushort_t*)d_out;
    ushort_t* alo = (ushort_t*)d_out + 4194304;
    ushort_t* bhi = (ushort_t*)(ws + WS_BHI);
    ushort_t* blo = (ushort_t*)(ws + WS_BLO);
    float*      enorm = ws + WS_ENORM;
    uint64_hip* keys  = (uint64_hip*)(ws + WS_KEYS);
    float*      lpart = ws + WS_LPART;

    conv_kernel<<<4096, 256, 0, stream>>>(x, cb, ahi, alo, bhi, blo, enorm, keys);
    vq_mfma_kernel<<<512, 256, 0, stream>>>(ahi, alo, bhi, blo, enorm, keys);
    finish_kernel<<<NROWS / 4, 256, 0, stream>>>(x, cb, keys,
                                                 out + OUT_IDX, out + OUT_Q,
                                                 out + OUT_MIND, lpart);
    loss_kernel<<<1, 256, 0, stream>>>(lpart, out + OUT_LOSS, out + OUT_COMMIT);
}

// Round 8
// 297.248 us; speedup vs baseline: 1.0409x; 1.0204x over previous
//
#include <hip/hip_runtime.h>

typedef __attribute__((ext_vector_type(8)))  short short8;   // 8 bf16 (4 VGPRs)
typedef __attribute__((ext_vector_type(16))) float f32x16;   // 32x32 MFMA acc
typedef unsigned short ushort_t;
typedef unsigned int uint32;
typedef unsigned long long uint64_hip;

#define NROWS 8192
#define NCODE 8192
#define DIM   512

// ---------------- d_out layout (floats) ----------------
#define OUT_Q      0
#define OUT_LOSS   4194304
#define OUT_IDX    4194305
#define OUT_MIND   4202497
#define OUT_COMMIT 4210689

// ---------------- ws layout (floats) ----------------
#define WS_ENORM  0           // 8192 floats
#define WS_KEYS   8192        // 8192 uint64 = 16384 floats
#define WS_BHI    26624       // 8192*512 bf16 = 2097152 floats
#define WS_BLO    2247680     // same (BK=32 tile layout, round-3 constants)

// ===========================================================================
__device__ inline uint32 bf16_rne(float f) {
    uint32 u = __float_as_uint(f);
    return (u + 0x7FFFu + ((u >> 16) & 1u)) >> 16;
}

__device__ inline void gload16(const ushort_t* g, ushort_t* l) {
    __builtin_amdgcn_global_load_lds(
        (const __attribute__((address_space(1))) void*)g,
        (__attribute__((address_space(3))) void*)l, 16, 0, 0);
}

// ===========================================================================
// Kernel 1 (round-3 verbatim layout): convert x and codebook into
// fragment-ordered bf16 hi/lo tiles. Tile = 128 rows x 32 k, 8 KB, 8 chunks
// of 1 KB: chunk c = (r32)*2 + k16; lane L = (row&31) + 32*((k>>3)&1) holds
// 8 consecutive k. (mfma_32x32x16 A/B fragment order — verified r3.)
// Extras: init argmin keys to +inf; zero the two loss accumulators.
__global__ __launch_bounds__(256) void conv_kernel(const float* __restrict__ x,
                                                   const float* __restrict__ cb,
                                                   ushort_t* __restrict__ ahi,
                                                   ushort_t* __restrict__ alo,
                                                   ushort_t* __restrict__ bhi,
                                                   ushort_t* __restrict__ blo,
                                                   float* __restrict__ enorm,
                                                   uint64_hip* __restrict__ keys,
                                                   float* __restrict__ out) {
    int gid  = blockIdx.x * 256 + threadIdx.x;   // 0..1048575
    if (gid < NROWS) keys[gid] = ~0ull;          // argmin key init
    if (gid == 0) { out[OUT_LOSS] = 0.0f; out[OUT_COMMIT] = 0.0f; }
    bool isA = gid < 524288;
    int g    = isA ? gid : gid - 524288;
    int row  = g >> 6;
    int lane = g & 63;
    int k0   = lane * 8;
    const float* src = (isA ? x : cb) + (size_t)row * DIM + k0;
    float v[8];
    *(float4*)&v[0] = *(const float4*)src;
    *(float4*)&v[4] = *(const float4*)(src + 4);
    float s = 0.0f;
    uint32 h[8], l[8];
    #pragma unroll
    for (int i = 0; i < 8; ++i) {
        s += v[i] * v[i];
        h[i] = bf16_rne(v[i]);
        float hf = __uint_as_float(h[i] << 16);
        l[i] = bf16_rne(v[i] - hf);
    }
    // round-3 fragment-ordered offset (BK=32 tiles of 4096 ushorts)
    int tile = (row >> 7) * 16 + (k0 >> 5);
    int rp = row & 127, kp = k0 & 31;
    int c  = (rp >> 5) * 2 + (kp >> 4);
    int L  = (rp & 31) + (((kp >> 3) & 1) << 5);
    size_t off = (size_t)tile * 4096 + c * 512 + L * 8;   // ushort units
    uint4 ph, pl;
    ph.x = h[0] | (h[1] << 16); ph.y = h[2] | (h[3] << 16);
    ph.z = h[4] | (h[5] << 16); ph.w = h[6] | (h[7] << 16);
    pl.x = l[0] | (l[1] << 16); pl.y = l[2] | (l[3] << 16);
    pl.z = l[4] | (l[5] << 16); pl.w = l[6] | (l[7] << 16);
    if (isA) {
        *(uint4*)(ahi + off) = ph;
        *(uint4*)(alo + off) = pl;
    } else {
        *(uint4*)(bhi + off) = ph;
        *(uint4*)(blo + off) = pl;
        #pragma unroll
        for (int o = 32; o > 0; o >>= 1) s += __shfl_down(s, o);
        if (lane == 0) enorm[row] = s;
    }
}

// ===========================================================================
// Kernel 2: round-3 MFMA distance-GEMM + fused per-row argmin, VERBATIM
// (the proven 189 us / MfmaUtil 51% configuration): grid 512, block 256
// (4 waves, wave tile 64x64 = 2x2 of 32x32x16), BK=32, 2 x 32 KB LDS dbuf,
// 16 ds_read_b128 + 24 MFMA per barrier interval, persistent best regs,
// slot-major LDS reduction. Only the tail differs: pack sortable key and
// atomicMin into keys[] (replaces pmin/pidx + combine kernel).
// XCD swizzle: XCD j = q%8 hosts bx in [8j,8j+8) -> 2 MB A stays L2-resident.
__global__ __launch_bounds__(256, 2) void vq_mfma_kernel(
        const ushort_t* __restrict__ ahi, const ushort_t* __restrict__ alo,
        const ushort_t* __restrict__ bhi, const ushort_t* __restrict__ blo,
        const float* __restrict__ enorm,
        uint64_hip* __restrict__ keys) {
    __shared__ __align__(16) ushort_t smem[32768];   // 64 KB = 2 x 32 KB buffers

    const int tid  = threadIdx.x;
    const int wave = tid >> 6, lane = tid & 63;
    const int l31  = lane & 31, half = lane >> 5;
    const int q  = blockIdx.x;
    const int bx = (q & 7) * 8 + (q >> 6);    // 0..63 row block; XCD = q%8
    const int by = (q >> 3) & 7;              // 0..7 col slice (1024 cols)
    const int wrow = (wave >> 1) * 64;
    const int wcol = (wave & 1) * 64;
    const int so = wave * 512 + lane * 8;     // ushort offset inside 4 KB chunk

    f32x16 acc[2][2];
    #pragma unroll
    for (int i = 0; i < 2; ++i)
        #pragma unroll
        for (int j = 0; j < 2; ++j)
            #pragma unroll
            for (int r = 0; r < 16; ++r) acc[i][j][r] = 0.0f;

    float bestd[32];
    int   besti[32];
    #pragma unroll
    for (int i = 0; i < 32; ++i) { bestd[i] = 3.4e38f; besti[i] = 0x7FFFFFFF; }

    // ---- stage tile n into buffer n&1 ----
    auto stage = [&](int n) {
        const int kb = n & 15;
        const int ctile = by * 8 + (n >> 4);
        const size_t at = (size_t)(bx * 16 + kb) * 4096;
        const size_t bt = (size_t)(ctile * 16 + kb) * 4096;
        ushort_t* S = smem + (n & 1) * 16384;
        gload16(ahi + at + so,        S + so);
        gload16(ahi + at + 2048 + so, S + 2048 + so);
        gload16(alo + at + so,        S + 4096 + so);
        gload16(alo + at + 2048 + so, S + 6144 + so);
        gload16(bhi + bt + so,        S + 8192 + so);
        gload16(bhi + bt + 2048 + so, S + 10240 + so);
        gload16(blo + bt + so,        S + 12288 + so);
        gload16(blo + bt + 2048 + so, S + 14336 + so);
    };

    stage(0);

    for (int n = 0; n < 128; ++n) {
        __syncthreads();                // drains stage(n); frees buffer (n+1)&1
        if (n + 1 < 128) stage(n + 1);  // async into other buffer, no wait

        ushort_t* S = smem + (n & 1) * 16384;
        #pragma unroll
        for (int k16 = 0; k16 < 2; ++k16) {
            short8 ah[2], al[2], bh[2], bl[2];
            #pragma unroll
            for (int ti = 0; ti < 2; ++ti) {
                int ca = ((wrow >> 5) + ti) * 2 + k16;
                ah[ti] = *(const short8*)&S[ca * 512 + lane * 8];
                al[ti] = *(const short8*)&S[4096 + ca * 512 + lane * 8];
            }
            #pragma unroll
            for (int tj = 0; tj < 2; ++tj) {
                int cb_ = ((wcol >> 5) + tj) * 2 + k16;
                bh[tj] = *(const short8*)&S[8192 + cb_ * 512 + lane * 8];
                bl[tj] = *(const short8*)&S[12288 + cb_ * 512 + lane * 8];
            }
            #pragma unroll
            for (int ti = 0; ti < 2; ++ti)
                #pragma unroll
                for (int tj = 0; tj < 2; ++tj) {
                    acc[ti][tj] = __builtin_amdgcn_mfma_f32_32x32x16_bf16(
                        ah[ti], bh[tj], acc[ti][tj], 0, 0, 0);
                    acc[ti][tj] = __builtin_amdgcn_mfma_f32_32x32x16_bf16(
                        ah[ti], bl[tj], acc[ti][tj], 0, 0, 0);
                    acc[ti][tj] = __builtin_amdgcn_mfma_f32_32x32x16_bf16(
                        al[ti], bh[tj], acc[ti][tj], 0, 0, 0);
                }
        }

        if ((n & 15) == 15) {
            // epilogue for col tile ct: dist' = ||e||^2 - 2*dot (xn drops out)
            const int ct = n >> 4;
            const int colbase = by * 1024 + ct * 128 + wcol;
            #pragma unroll
            for (int tj = 0; tj < 2; ++tj) {
                const int ci = colbase + tj * 32 + l31;
                const float en = enorm[ci];
                #pragma unroll
                for (int ti = 0; ti < 2; ++ti)
                    #pragma unroll
                    for (int reg = 0; reg < 16; ++reg) {
                        float d = en - 2.0f * acc[ti][tj][reg];
                        int s = ti * 16 + reg;
                        if (d < bestd[s]) { bestd[s] = d; besti[s] = ci; }
                    }
            }
            #pragma unroll
            for (int i = 0; i < 2; ++i)
                #pragma unroll
                for (int j = 0; j < 2; ++j)
                    #pragma unroll
                    for (int r = 0; r < 16; ++r) acc[i][j][r] = 0.0f;
        }
    }

    // ---- block argmin reduction: 64 candidates per row ----
    // slot-major [slot][128 rows]: conflict-free reads in the scan phase
    float* rd = (float*)smem;           // 64*128 floats = 32 KB
    int*   ri = (int*)smem + 8192;      // 64*128 ints   = 32 KB
    __syncthreads();
    const int slot = (wave & 1) * 32 + l31;
    #pragma unroll
    for (int ti = 0; ti < 2; ++ti)
        #pragma unroll
        for (int reg = 0; reg < 16; ++reg) {
            int row = wrow + ti * 32 + (reg & 3) + 8 * (reg >> 2) + 4 * half;
            rd[slot * 128 + row] = bestd[ti * 16 + reg];
            ri[slot * 128 + row] = besti[ti * 16 + reg];
        }
    __syncthreads();
    if (tid < 128) {
        float bd = rd[tid];
        int   bi = ri[tid];
        #pragma unroll 8
        for (int t = 1; t < 64; ++t) {
            float d = rd[t * 128 + tid];
            int  ii = ri[t * 128 + tid];
            if (d < bd || (d == bd && ii < bi)) { bd = d; bi = ii; }
        }
        uint32 u = __float_as_uint(bd);
        u = ((int)u < 0) ? ~u : (u | 0x80000000u);
        uint64_hip key = ((uint64_hip)u << 13) | (uint32)bi;
        atomicMin(&keys[(size_t)bx * 128 + tid], key);
    }
}

// ===========================================================================
// Kernel 3: decode key -> idx, gather codebook row, exact fp32 ||x-e||^2 ->
// min_distances; atomicAdd loss partials (loss = 1.25 * commit since
// loss_vq == loss_commit numerically). One 64-lane group per row.
__global__ __launch_bounds__(256) void finish_kernel(const float* __restrict__ x,
                                                     const float* __restrict__ cb,
                                                     const uint64_hip* __restrict__ keys,
                                                     float* __restrict__ out_idx,
                                                     float* __restrict__ qout,
                                                     float* __restrict__ out_mind,
                                                     float* __restrict__ out) {
    __shared__ float sred[4];
    int row  = blockIdx.x * 4 + (threadIdx.x >> 6);
    int lane = threadIdx.x & 63;
    int idx  = (int)(keys[row] & 0x1FFFull);
    if (lane == 0) out_idx[row] = (float)idx;

    const float4* e4 = (const float4*)(cb + (size_t)idx * DIM);
    const float4* x4 = (const float4*)(x + (size_t)row * DIM);
    float4* q4 = (float4*)(qout + (size_t)row * DIM);
    float s = 0.0f;
    #pragma unroll
    for (int u = 0; u < 2; ++u) {
        float4 e  = e4[lane + u * 64];
        float4 xv = x4[lane + u * 64];
        q4[lane + u * 64] = e;
        float dx = xv.x - e.x, dy = xv.y - e.y, dz = xv.z - e.z, dw = xv.w - e.w;
        s += dx * dx + dy * dy + dz * dz + dw * dw;
    }
    #pragma unroll
    for (int o = 32; o > 0; o >>= 1) s += __shfl_down(s, o);
    if (lane == 0) { sred[threadIdx.x >> 6] = s; out_mind[row] = s; }
    __syncthreads();
    if (threadIdx.x == 0) {
        float bs = sred[0] + sred[1] + sred[2] + sred[3];
        atomicAdd(out + OUT_COMMIT, bs);
        atomicAdd(out + OUT_LOSS, 1.25f * bs);
    }
}

// ===========================================================================
extern "C" void kernel_launch(void* const* d_in, const int* in_sizes, int n_in,
                              void* d_out, int out_size, void* d_ws, size_t ws_size,
                              hipStream_t stream) {
    const float* x  = (const float*)d_in[0];
    const float* cb = (const float*)d_in[1];
    float* out = (float*)d_out;
    float* ws  = (float*)d_ws;

    // A hi/lo staged in the quantized-output region (rewritten by finish_kernel)
    ushort_t* ahi = (ushort_t*)d_out;
    ushort_t* alo = (ushort_t*)d_out + 4194304;
    ushort_t* bhi = (ushort_t*)(ws + WS_BHI);
    ushort_t* blo = (ushort_t*)(ws + WS_BLO);
    float*      enorm = ws + WS_ENORM;
    uint64_hip* keys  = (uint64_hip*)(ws + WS_KEYS);

    conv_kernel<<<4096, 256, 0, stream>>>(x, cb, ahi, alo, bhi, blo, enorm, keys, out);
    vq_mfma_kernel<<<512, 256, 0, stream>>>(ahi, alo, bhi, blo, enorm, keys);
    finish_kernel<<<NROWS / 4, 256, 0, stream>>>(x, cb, keys,
                                                 out + OUT_IDX, out + OUT_Q,
                                                 out + OUT_MIND, out);
}